// Round 1
// baseline (889.343 us; speedup 1.0000x reference)
//
#include <hip/hip_runtime.h>
#include <cstdint>
#include <cfloat>

#define F 16
#define B 4096
#define D 256
#define K 1024

// ---- workspace layout (bytes) ----
// [0, 16MB)            wt   : F*K*D floats (transposed codebook, [f][k][d])
// [16MB, +64KB)        wsq  : F*K floats   (||w_k||^2, fp32, for candidate scoring)
// [+512KB)             top2 : F*B int2     (top-2 candidate indices per row)
// [+8B]                lossAcc : double
#define WT_OFF   0
#define WSQ_OFF  16777216
#define TOP2_OFF 16842752
#define LOSS_OFF 17367040

// ---------------- init: zero the loss accumulator ----------------
__global__ void init_kernel(double* lossAcc) {
    if (threadIdx.x == 0) *lossAcc = 0.0;
}

// ---------------- transpose codebook: wt[f][k][d] = w[f][d][k] ----------------
__global__ void transpose_w(const float* __restrict__ w, float* __restrict__ wt) {
    __shared__ float sd[32][33];
    int f  = blockIdx.z;
    int k0 = blockIdx.x * 32;
    int d0 = blockIdx.y * 32;
    const float* wf = w  + (size_t)f * D * K;
    float*      wtf = wt + (size_t)f * K * D;
    int tx = threadIdx.x;   // 0..31 (k within tile on load, d within tile on store)
    int ty = threadIdx.y;   // 0..7
#pragma unroll
    for (int i = 0; i < 4; ++i) {
        int d = ty + i * 8;
        sd[d][tx] = wf[(size_t)(d0 + d) * K + (k0 + tx)];
    }
    __syncthreads();
#pragma unroll
    for (int i = 0; i < 4; ++i) {
        int k = ty + i * 8;
        wtf[(size_t)(k0 + k) * D + (d0 + tx)] = sd[tx][k];
    }
}

// ---------------- ||w_k||^2 per (f,k), fp32 (selection only; fp64 refine later) ----
__global__ void compute_wsq(const float* __restrict__ w, float* __restrict__ wsq) {
    int idx = blockIdx.x * blockDim.x + threadIdx.x;   // f*K + k
    int f = idx >> 10, k = idx & (K - 1);
    const float* wf = w + (size_t)f * D * K + k;
    float acc = 0.f;
#pragma unroll 8
    for (int d = 0; d < D; ++d) {
        float v = wf[(size_t)d * K];
        acc = fmaf(v, v, acc);
    }
    wsq[idx] = acc;
}

// ---------------- fused fp32 GEMM + per-row top-2 ----------------
// score(k) = wsq[k] - 2 * <x, w_k>   (row-constant ||x||^2 omitted: monotone shift)
#define BM 64
#define BN 64
#define DK 32
#define XPAD 260   // 256 + 4 pad: breaks row-stride bank aliasing, keeps 16B alignment

__global__ __launch_bounds__(256, 2) void gemm_top2(
        const float* __restrict__ x, const float* __restrict__ w,
        const float* __restrict__ wsq, int2* __restrict__ top2) {
    __shared__ float Xs[BM * XPAD];   // 66560 B
    __shared__ float Ws[DK * BN];     //  8192 B
    int f   = blockIdx.y;
    int m0  = blockIdx.x * BM;
    int tid = threadIdx.x;
    int ty  = tid >> 4;     // 0..15 -> rows ty*4..ty*4+3
    int tx  = tid & 15;     // 0..15 -> cols tx*4..tx*4+3 within n-chunk

    const float* xf = x + ((size_t)f * B + m0) * D;
    const float* wf = w + (size_t)f * D * K;

    // stage X tile [64][256], float4-coalesced
#pragma unroll
    for (int i = 0; i < 16; ++i) {
        int id = tid + i * 256;            // float4 id 0..4095; id = r*64 + c4
        int r = id >> 6, c4 = id & 63;
        float4 v = ((const float4*)xf)[id];
        *(float4*)(&Xs[r * XPAD + c4 * 4]) = v;
    }

    float v1[4], v2[4];
    int   i1[4], i2[4];
#pragma unroll
    for (int r = 0; r < 4; ++r) {
        v1[r] = FLT_MAX; v2[r] = FLT_MAX;
        i1[r] = 0x7fffffff; i2[r] = 0x7fffffff;
    }

    for (int n0 = 0; n0 < K; n0 += BN) {
        float acc[4][4] = {{0.f}};
        for (int d0 = 0; d0 < D; d0 += DK) {
            __syncthreads();
            // stage W chunk [32][64]: 512 float4s, 2 per thread, coalesced
#pragma unroll
            for (int i = 0; i < 2; ++i) {
                int id = tid + i * 256;        // 0..511
                int dr = id >> 4, nc4 = id & 15;
                ((float4*)Ws)[id] =
                    ((const float4*)(wf + (size_t)(d0 + dr) * K + n0))[nc4];
            }
            __syncthreads();
#pragma unroll
            for (int dd = 0; dd < DK; dd += 4) {
                float4 xv[4], wv[4];
#pragma unroll
                for (int r = 0; r < 4; ++r)
                    xv[r] = *(const float4*)(&Xs[(ty * 4 + r) * XPAD + d0 + dd]);
#pragma unroll
                for (int q = 0; q < 4; ++q)
                    wv[q] = *(const float4*)(&Ws[(dd + q) * BN + tx * 4]);
#pragma unroll
                for (int dq = 0; dq < 4; ++dq) {
#pragma unroll
                    for (int r = 0; r < 4; ++r) {
                        float a = ((const float*)&xv[r])[dq];
                        acc[r][0] = fmaf(a, ((const float*)&wv[dq])[0], acc[r][0]);
                        acc[r][1] = fmaf(a, ((const float*)&wv[dq])[1], acc[r][1]);
                        acc[r][2] = fmaf(a, ((const float*)&wv[dq])[2], acc[r][2]);
                        acc[r][3] = fmaf(a, ((const float*)&wv[dq])[3], acc[r][3]);
                    }
                }
            }
        }
        // epilogue: scores + top-2 update (indices ascend within thread -> '<' keeps earliest)
        float4 wq = ((const float4*)(wsq + (size_t)f * K + n0))[tx];
#pragma unroll
        for (int r = 0; r < 4; ++r) {
#pragma unroll
            for (int c = 0; c < 4; ++c) {
                float s = fmaf(-2.f, acc[r][c], ((const float*)&wq)[c]);
                int idx = n0 + tx * 4 + c;
                if (s < v1[r]) {
                    v2[r] = v1[r]; i2[r] = i1[r];
                    v1[r] = s;     i1[r] = idx;
                } else if (s < v2[r]) {
                    v2[r] = s;     i2[r] = idx;
                }
            }
        }
    }

    // cross-thread top-2 merge over the 16 lanes sharing each row (same ty)
#pragma unroll
    for (int off = 1; off < 16; off <<= 1) {
#pragma unroll
        for (int r = 0; r < 4; ++r) {
            float ov1 = __shfl_xor(v1[r], off);
            int   oi1 = __shfl_xor(i1[r], off);
            float ov2 = __shfl_xor(v2[r], off);
            int   oi2 = __shfl_xor(i2[r], off);
            bool sw = (ov1 < v1[r]) || (ov1 == v1[r] && oi1 < i1[r]);
            float a1 = sw ? ov1 : v1[r]; int a1i = sw ? oi1 : i1[r];
            float b1 = sw ? v1[r] : ov1; int b1i = sw ? i1[r] : oi1;
            float a2 = sw ? ov2 : v2[r]; int a2i = sw ? oi2 : i2[r];
            bool rp = (b1 < a2) || (b1 == a2 && b1i < a2i);
            v1[r] = a1;            i1[r] = a1i;
            v2[r] = rp ? b1 : a2;  i2[r] = rp ? b1i : a2i;
        }
    }
    if (tx == 0) {
#pragma unroll
        for (int r = 0; r < 4; ++r)
            top2[(size_t)f * B + m0 + ty * 4 + r] = make_int2(i1[r], i2[r]);
    }
}

// ---------------- fp64 refine + gather + loss ----------------
// one wave per row; exact ||x - w||^2 for both candidates decides the argmin.
__global__ __launch_bounds__(256) void refine_gather(
        const float* __restrict__ x, const float* __restrict__ wt,
        const int2* __restrict__ top2, float* __restrict__ out,
        double* __restrict__ lossAcc) {
    __shared__ double lpart[4];
    int tid  = threadIdx.x;
    int wv   = tid >> 6;
    int lane = tid & 63;
    size_t row = (size_t)blockIdx.x * 4 + wv;   // 0..F*B-1
    int f = (int)(row >> 12);                   // row / B
    int2 cand = top2[row];
    const float* xr = x  + row * D;
    const float* w1 = wt + ((size_t)f * K + cand.x) * D;
    const float* w2 = wt + ((size_t)f * K + cand.y) * D;

    float4 xv = ((const float4*)xr)[lane];
    float4 a  = ((const float4*)w1)[lane];
    float4 b  = ((const float4*)w2)[lane];
    double s1 = 0.0, s2 = 0.0;
#pragma unroll
    for (int j = 0; j < 4; ++j) {
        double d1 = (double)((const float*)&xv)[j] - (double)((const float*)&a)[j];
        double d2 = (double)((const float*)&xv)[j] - (double)((const float*)&b)[j];
        s1 = fma(d1, d1, s1);
        s2 = fma(d2, d2, s2);
    }
#pragma unroll
    for (int off = 1; off < 64; off <<= 1) {
        s1 += __shfl_xor(s1, off);
        s2 += __shfl_xor(s2, off);
    }
    bool pick2 = (s2 < s1) || (s2 == s1 && cand.y < cand.x);
    float4 q = pick2 ? b : a;
    ((float4*)(out + row * D))[lane] = q;

    double sel = pick2 ? s2 : s1;
    if (lane == 0) lpart[wv] = sel;
    __syncthreads();
    if (tid == 0) {
        double t = lpart[0] + lpart[1] + lpart[2] + lpart[3];
        atomicAdd(lossAcc, t);
    }
}

// ---------------- finalize loss ----------------
__global__ void finish_loss(const double* __restrict__ lossAcc,
                            float* __restrict__ out_loss) {
    if (threadIdx.x == 0)
        *out_loss = (float)(0.25 * (*lossAcc) / ((double)F * (double)B * (double)D));
}

extern "C" void kernel_launch(void* const* d_in, const int* in_sizes, int n_in,
                              void* d_out, int out_size, void* d_ws, size_t ws_size,
                              hipStream_t stream) {
    const float* x = (const float*)d_in[0];   // [F,B,D]
    const float* w = (const float*)d_in[1];   // [F,D,K]
    float* out = (float*)d_out;               // [F,B,D] then loss scalar

    float*  wt      = (float*)((char*)d_ws + WT_OFF);
    float*  wsq     = (float*)((char*)d_ws + WSQ_OFF);
    int2*   top2    = (int2*)((char*)d_ws + TOP2_OFF);
    double* lossAcc = (double*)((char*)d_ws + LOSS_OFF);

    init_kernel<<<1, 64, 0, stream>>>(lossAcc);
    transpose_w<<<dim3(K / 32, D / 32, F), dim3(32, 8), 0, stream>>>(w, wt);
    compute_wsq<<<dim3(F * K / 256), 256, 0, stream>>>(w, wsq);
    gemm_top2<<<dim3(B / BM, F), 256, 0, stream>>>(x, w, wsq, top2);
    refine_gather<<<dim3(F * B / 4), 256, 0, stream>>>(x, wt, top2, out, lossAcc);
    finish_loss<<<1, 64, 0, stream>>>(lossAcc, out + (size_t)F * B * D);
}

// Round 2
// 587.435 us; speedup vs baseline: 1.5139x; 1.5139x over previous
//
#include <hip/hip_runtime.h>
#include <hip/hip_bf16.h>
#include <cstdint>
#include <cfloat>

#define F 16
#define B 4096
#define D 256
#define K 1024

typedef __attribute__((ext_vector_type(8))) short bf16x8;
typedef __attribute__((ext_vector_type(4))) float f32x4;

// ---- fast-path workspace layout (bytes) ----
#define XH_OFF   0u            // F*B*D bf16 = 33554432
#define XL_OFF   33554432u
#define WHT_OFF  67108864u     // F*K*D bf16 (transposed [f][k][d]) = 8388608
#define WLT_OFF  75497472u
#define WT_OFF   83886080u     // F*K*D fp32 (transposed) = 16777216
#define WSQ_OFF  100663296u    // F*K fp32
#define TOP2_OFF 100728832u    // F*B int2
#define LOSS_OFF 101253120u
#define WS_NEED  101253128u

// ---- fallback (round-1) layout ----
#define WT2_OFF   0u
#define WSQ2_OFF  16777216u
#define TOP22_OFF 16842752u
#define LOSS2_OFF 17367040u

__device__ __forceinline__ void async_load16(const void* g, void* l) {
    __builtin_amdgcn_global_load_lds(
        (const __attribute__((address_space(1))) void*)g,
        (__attribute__((address_space(3))) void*)l, 16, 0, 0);
}

// ---------------- init ----------------
__global__ void init_kernel(double* lossAcc) {
    if (threadIdx.x == 0) *lossAcc = 0.0;
}

// ---------------- split x into bf16 hi/lo ----------------
__global__ void split_x(const float* __restrict__ x, ushort* __restrict__ xh,
                        ushort* __restrict__ xl) {
    int i = (blockIdx.x * 256 + threadIdx.x) * 4;
    float4 v = *(const float4*)(x + i);
    ushort4 h, l;
#pragma unroll
    for (int j = 0; j < 4; ++j) {
        float fv = ((const float*)&v)[j];
        __hip_bfloat16 hb = __float2bfloat16(fv);
        float hf = __bfloat162float(hb);
        __hip_bfloat16 lb = __float2bfloat16(fv - hf);
        ((ushort*)&h)[j] = *(ushort*)&hb;
        ((ushort*)&l)[j] = *(ushort*)&lb;
    }
    *(ushort4*)(xh + i) = h;
    *(ushort4*)(xl + i) = l;
}

// ---------------- transpose w -> wt fp32 [f][k][d], + bf16 hi/lo ----------------
__global__ void transpose_split_w(const float* __restrict__ w, float* __restrict__ wt,
                                  ushort* __restrict__ whT, ushort* __restrict__ wlT) {
    __shared__ float sd[32][33];
    int f  = blockIdx.z;
    int k0 = blockIdx.x * 32;
    int d0 = blockIdx.y * 32;
    const float* wf = w + (size_t)f * D * K;
    size_t obase = (size_t)f * K * D;
    int tx = threadIdx.x, ty = threadIdx.y;
#pragma unroll
    for (int i = 0; i < 4; ++i) {
        int d = ty + i * 8;
        sd[d][tx] = wf[(size_t)(d0 + d) * K + (k0 + tx)];
    }
    __syncthreads();
#pragma unroll
    for (int i = 0; i < 4; ++i) {
        int k = ty + i * 8;
        float v = sd[tx][k];
        size_t o = obase + (size_t)(k0 + k) * D + (d0 + tx);
        wt[o] = v;
        __hip_bfloat16 hb = __float2bfloat16(v);
        float hf = __bfloat162float(hb);
        __hip_bfloat16 lb = __float2bfloat16(v - hf);
        whT[o] = *(ushort*)&hb;
        wlT[o] = *(ushort*)&lb;
    }
}

// ---------------- ||w_k||^2 fp32 ----------------
__global__ void compute_wsq(const float* __restrict__ w, float* __restrict__ wsq) {
    int idx = blockIdx.x * blockDim.x + threadIdx.x;
    int f = idx >> 10;
    int k = idx & (K - 1);
    const float* wf = w + (size_t)f * D * K + k;
    float acc = 0.f;
#pragma unroll 8
    for (int d = 0; d < D; ++d) {
        float v = wf[(size_t)d * K];
        acc = fmaf(v, v, acc);
    }
    wsq[idx] = acc;
}

// ---------------- MFMA split-bf16 GEMM + top-2 ----------------
// score(n) = wsq[n] - 2*(xh.wh + xh.wl + xl.wh)
__global__ __launch_bounds__(256, 2) void gemm_mfma_top2(
        const ushort* __restrict__ xh, const ushort* __restrict__ xl,
        const ushort* __restrict__ whT, const ushort* __restrict__ wlT,
        const float* __restrict__ wsq, int2* __restrict__ top2)
{
    // 4 tiles of [128 rows][64 cols] bf16, XOR-swizzled 16B segments: 64 KiB
    __shared__ ushort lds[4 * 128 * 64];
    const int f    = blockIdx.y;
    const int m0   = blockIdx.x * 128;
    const int tid  = threadIdx.x;
    const int wave = tid >> 6, lane = tid & 63;
    const int mw   = wave >> 1, nw = wave & 1;
    const int quad = lane >> 4, l15 = lane & 15;

    // staging sources: wave w stages tile w (Ah, Al, Wh, Wl)
    const ushort* srcs[4] = {
        xh  + ((size_t)f * B + m0) * D,
        xl  + ((size_t)f * B + m0) * D,
        whT + (size_t)f * K * D,
        wlT + (size_t)f * K * D };
    ushort* ltile = lds + wave * (128 * 64);
    const bool isW = (wave >= 2);

    float v1[16], v2[16];
    int   i1[16], i2[16];
#pragma unroll
    for (int s = 0; s < 16; ++s) {
        v1[s] = FLT_MAX; v2[s] = FLT_MAX; i1[s] = 0x7fffffff; i2[s] = 0x7fffffff;
    }

    for (int n0 = 0; n0 < K; n0 += 128) {
        f32x4 acc[4][4];
#pragma unroll
        for (int mt = 0; mt < 4; ++mt)
#pragma unroll
            for (int nt = 0; nt < 4; ++nt)
                acc[mt][nt] = (f32x4){0.f, 0.f, 0.f, 0.f};

        const ushort* gbase = isW ? srcs[wave] + (size_t)n0 * D : srcs[wave];

        for (int d0 = 0; d0 < D; d0 += 64) {
            __syncthreads();
            // stage this wave's tile: 16 x 1KiB wave-instructions
#pragma unroll
            for (int wi = 0; wi < 16; ++wi) {
                int linear = wi * 64 + lane;
                int row = linear >> 3, sl = linear & 7;
                int sg = sl ^ (row & 7);
                const ushort* g = gbase + (size_t)row * D + d0 + sg * 8;
                async_load16(g, ltile + wi * 512 + lane * 8);
            }
            __syncthreads();

#pragma unroll
            for (int ks = 0; ks < 2; ++ks) {
                bf16x8 ah[4], al[4];
#pragma unroll
                for (int mt = 0; mt < 4; ++mt) {
                    int row = mw * 64 + mt * 16 + l15;
                    int seg = ks * 4 + quad;
                    int off = row * 64 + ((seg ^ (row & 7)) * 8);
                    ah[mt] = *(const bf16x8*)(lds + off);
                    al[mt] = *(const bf16x8*)(lds + 8192 + off);
                }
#pragma unroll
                for (int nt = 0; nt < 4; ++nt) {
                    int row = nw * 64 + nt * 16 + l15;
                    int seg = ks * 4 + quad;
                    int off = row * 64 + ((seg ^ (row & 7)) * 8);
                    bf16x8 bh = *(const bf16x8*)(lds + 16384 + off);
                    bf16x8 bl = *(const bf16x8*)(lds + 24576 + off);
#pragma unroll
                    for (int mt = 0; mt < 4; ++mt) {
                        acc[mt][nt] = __builtin_amdgcn_mfma_f32_16x16x32_bf16(ah[mt], bh, acc[mt][nt], 0, 0, 0);
                        acc[mt][nt] = __builtin_amdgcn_mfma_f32_16x16x32_bf16(ah[mt], bl, acc[mt][nt], 0, 0, 0);
                        acc[mt][nt] = __builtin_amdgcn_mfma_f32_16x16x32_bf16(al[mt], bh, acc[mt][nt], 0, 0, 0);
                    }
                }
            }
        }

        // epilogue: fold this 128-column chunk into per-lane running top-2
        float wq[4];
#pragma unroll
        for (int nt = 0; nt < 4; ++nt)
            wq[nt] = wsq[f * K + n0 + nw * 64 + nt * 16 + l15];
#pragma unroll
        for (int mt = 0; mt < 4; ++mt) {
#pragma unroll
            for (int r = 0; r < 4; ++r) {
                int s = mt * 4 + r;
#pragma unroll
                for (int nt = 0; nt < 4; ++nt) {
                    float sc = fmaf(-2.f, acc[mt][nt][r], wq[nt]);
                    int idx = n0 + nw * 64 + nt * 16 + l15;
                    if (sc < v1[s]) { v2[s] = v1[s]; i2[s] = i1[s]; v1[s] = sc; i1[s] = idx; }
                    else if (sc < v2[s]) { v2[s] = sc; i2[s] = idx; }
                }
            }
        }
    }

    // cross-lane merge among the 16 lanes sharing each row (same quad)
#pragma unroll
    for (int s = 0; s < 16; ++s) {
#pragma unroll
        for (int off = 1; off < 16; off <<= 1) {
            float ov1 = __shfl_xor(v1[s], off);
            int   oi1 = __shfl_xor(i1[s], off);
            float ov2 = __shfl_xor(v2[s], off);
            int   oi2 = __shfl_xor(i2[s], off);
            bool sw = (ov1 < v1[s]) || (ov1 == v1[s] && oi1 < i1[s]);
            float a1 = sw ? ov1 : v1[s]; int a1i = sw ? oi1 : i1[s];
            float b1 = sw ? v1[s] : ov1; int b1i = sw ? i1[s] : oi1;
            float a2 = sw ? ov2 : v2[s]; int a2i = sw ? oi2 : i2[s];
            bool rp = (b1 < a2) || (b1 == a2 && b1i < a2i);
            v1[s] = a1;            i1[s] = a1i;
            v2[s] = rp ? b1 : a2;  i2[s] = rp ? b1i : a2i;
        }
    }

    // cross-wave (nw) merge via LDS; one writer lane (l15==0) per row-group
    __syncthreads();
    float* shv = (float*)lds;   // [2 mw][64 rows][4]: v1,i1,v2,i2
    if (nw == 1 && l15 == 0) {
#pragma unroll
        for (int mt = 0; mt < 4; ++mt)
#pragma unroll
            for (int r = 0; r < 4; ++r) {
                int s = mt * 4 + r;
                int rl = mt * 16 + quad * 4 + r;
                int base = (mw * 64 + rl) * 4;
                shv[base + 0] = v1[s];
                ((int*)shv)[base + 1] = i1[s];
                shv[base + 2] = v2[s];
                ((int*)shv)[base + 3] = i2[s];
            }
    }
    __syncthreads();
    if (nw == 0 && l15 == 0) {
#pragma unroll
        for (int mt = 0; mt < 4; ++mt)
#pragma unroll
            for (int r = 0; r < 4; ++r) {
                int s = mt * 4 + r;
                int rl = mt * 16 + quad * 4 + r;
                int base = (mw * 64 + rl) * 4;
                float ov1 = shv[base + 0];
                int   oi1 = ((int*)shv)[base + 1];
                float ov2 = shv[base + 2];
                int   oi2 = ((int*)shv)[base + 3];
                bool sw = (ov1 < v1[s]) || (ov1 == v1[s] && oi1 < i1[s]);
                float a1 = sw ? ov1 : v1[s]; int a1i = sw ? oi1 : i1[s];
                float b1 = sw ? v1[s] : ov1; int b1i = sw ? i1[s] : oi1;
                float a2 = sw ? ov2 : v2[s]; int a2i = sw ? oi2 : i2[s];
                bool rp = (b1 < a2) || (b1 == a2 && b1i < a2i);
                int m1i = a1i;
                int m2i = rp ? b1i : a2i;
                top2[(size_t)f * B + m0 + mw * 64 + rl] = make_int2(m1i, m2i);
            }
    }
}

// ---------------- fallback fp32 GEMM + top-2 (round-1) ----------------
#define BM 64
#define BN 64
#define DK 32
#define XPAD 260

__global__ __launch_bounds__(256, 2) void gemm_top2(
        const float* __restrict__ x, const float* __restrict__ w,
        const float* __restrict__ wsq, int2* __restrict__ top2) {
    __shared__ float Xs[BM * XPAD];
    __shared__ float Ws[DK * BN];
    int f   = blockIdx.y;
    int m0  = blockIdx.x * BM;
    int tid = threadIdx.x;
    int ty  = tid >> 4;
    int tx  = tid & 15;
    const float* xf = x + ((size_t)f * B + m0) * D;
    const float* wf = w + (size_t)f * D * K;
#pragma unroll
    for (int i = 0; i < 16; ++i) {
        int id = tid + i * 256;
        int r = id >> 6, c4 = id & 63;
        float4 v = ((const float4*)xf)[id];
        *(float4*)(&Xs[r * XPAD + c4 * 4]) = v;
    }
    float v1[4], v2[4];
    int   i1[4], i2[4];
#pragma unroll
    for (int r = 0; r < 4; ++r) {
        v1[r] = FLT_MAX; v2[r] = FLT_MAX; i1[r] = 0x7fffffff; i2[r] = 0x7fffffff;
    }
    for (int n0 = 0; n0 < K; n0 += BN) {
        float acc[4][4] = {{0.f}};
        for (int d0 = 0; d0 < D; d0 += DK) {
            __syncthreads();
#pragma unroll
            for (int i = 0; i < 2; ++i) {
                int id = tid + i * 256;
                int dr = id >> 4, nc4 = id & 15;
                ((float4*)Ws)[id] = ((const float4*)(wf + (size_t)(d0 + dr) * K + n0))[nc4];
            }
            __syncthreads();
#pragma unroll
            for (int dd = 0; dd < DK; dd += 4) {
                float4 xv[4], wv[4];
#pragma unroll
                for (int r = 0; r < 4; ++r)
                    xv[r] = *(const float4*)(&Xs[(ty * 4 + r) * XPAD + d0 + dd]);
#pragma unroll
                for (int q = 0; q < 4; ++q)
                    wv[q] = *(const float4*)(&Ws[(dd + q) * BN + tx * 4]);
#pragma unroll
                for (int dq = 0; dq < 4; ++dq)
#pragma unroll
                    for (int r = 0; r < 4; ++r) {
                        float a = ((const float*)&xv[r])[dq];
                        acc[r][0] = fmaf(a, ((const float*)&wv[dq])[0], acc[r][0]);
                        acc[r][1] = fmaf(a, ((const float*)&wv[dq])[1], acc[r][1]);
                        acc[r][2] = fmaf(a, ((const float*)&wv[dq])[2], acc[r][2]);
                        acc[r][3] = fmaf(a, ((const float*)&wv[dq])[3], acc[r][3]);
                    }
            }
        }
        float4 wq = ((const float4*)(wsq + (size_t)f * K + n0))[tx];
#pragma unroll
        for (int r = 0; r < 4; ++r)
#pragma unroll
            for (int c = 0; c < 4; ++c) {
                float s = fmaf(-2.f, acc[r][c], ((const float*)&wq)[c]);
                int idx = n0 + tx * 4 + c;
                if (s < v1[r]) { v2[r] = v1[r]; i2[r] = i1[r]; v1[r] = s; i1[r] = idx; }
                else if (s < v2[r]) { v2[r] = s; i2[r] = idx; }
            }
    }
#pragma unroll
    for (int off = 1; off < 16; off <<= 1)
#pragma unroll
        for (int r = 0; r < 4; ++r) {
            float ov1 = __shfl_xor(v1[r], off);
            int   oi1 = __shfl_xor(i1[r], off);
            float ov2 = __shfl_xor(v2[r], off);
            int   oi2 = __shfl_xor(i2[r], off);
            bool sw = (ov1 < v1[r]) || (ov1 == v1[r] && oi1 < i1[r]);
            float a1 = sw ? ov1 : v1[r]; int a1i = sw ? oi1 : i1[r];
            float b1 = sw ? v1[r] : ov1; int b1i = sw ? i1[r] : oi1;
            float a2 = sw ? ov2 : v2[r]; int a2i = sw ? oi2 : i2[r];
            bool rp = (b1 < a2) || (b1 == a2 && b1i < a2i);
            v1[r] = a1;            i1[r] = a1i;
            v2[r] = rp ? b1 : a2;  i2[r] = rp ? b1i : a2i;
        }
    if (tx == 0)
#pragma unroll
        for (int r = 0; r < 4; ++r)
            top2[(size_t)f * B + m0 + ty * 4 + r] = make_int2(i1[r], i2[r]);
}

// ---------------- fp32 transpose only (fallback) ----------------
__global__ void transpose_w(const float* __restrict__ w, float* __restrict__ wt) {
    __shared__ float sd[32][33];
    int f  = blockIdx.z;
    int k0 = blockIdx.x * 32;
    int d0 = blockIdx.y * 32;
    const float* wf = w  + (size_t)f * D * K;
    float*      wtf = wt + (size_t)f * K * D;
    int tx = threadIdx.x, ty = threadIdx.y;
#pragma unroll
    for (int i = 0; i < 4; ++i) {
        int d = ty + i * 8;
        sd[d][tx] = wf[(size_t)(d0 + d) * K + (k0 + tx)];
    }
    __syncthreads();
#pragma unroll
    for (int i = 0; i < 4; ++i) {
        int k = ty + i * 8;
        wtf[(size_t)(k0 + k) * D + (d0 + tx)] = sd[tx][k];
    }
}

// ---------------- fp64 refine + gather + loss ----------------
__global__ __launch_bounds__(256) void refine_gather(
        const float* __restrict__ x, const float* __restrict__ wt,
        const int2* __restrict__ top2, float* __restrict__ out,
        double* __restrict__ lossAcc) {
    __shared__ double lpart[4];
    int tid  = threadIdx.x;
    int wv   = tid >> 6;
    int lane = tid & 63;
    size_t row = (size_t)blockIdx.x * 4 + wv;
    int f = (int)(row >> 12);
    int2 cand = top2[row];
    const float* xr = x  + row * D;
    const float* w1 = wt + ((size_t)f * K + cand.x) * D;
    const float* w2 = wt + ((size_t)f * K + cand.y) * D;
    float4 xv = ((const float4*)xr)[lane];
    float4 a  = ((const float4*)w1)[lane];
    float4 b  = ((const float4*)w2)[lane];
    double s1 = 0.0, s2 = 0.0;
#pragma unroll
    for (int j = 0; j < 4; ++j) {
        double d1 = (double)((const float*)&xv)[j] - (double)((const float*)&a)[j];
        double d2 = (double)((const float*)&xv)[j] - (double)((const float*)&b)[j];
        s1 = fma(d1, d1, s1);
        s2 = fma(d2, d2, s2);
    }
#pragma unroll
    for (int off = 1; off < 64; off <<= 1) {
        s1 += __shfl_xor(s1, off);
        s2 += __shfl_xor(s2, off);
    }
    bool pick2 = (s2 < s1) || (s2 == s1 && cand.y < cand.x);
    float4 q = pick2 ? b : a;
    ((float4*)(out + row * D))[lane] = q;
    double sel = pick2 ? s2 : s1;
    if (lane == 0) lpart[wv] = sel;
    __syncthreads();
    if (tid == 0) {
        double t = lpart[0] + lpart[1] + lpart[2] + lpart[3];
        atomicAdd(lossAcc, t);
    }
}

__global__ void finish_loss(const double* __restrict__ lossAcc,
                            float* __restrict__ out_loss) {
    if (threadIdx.x == 0)
        *out_loss = (float)(0.25 * (*lossAcc) / ((double)F * (double)B * (double)D));
}

extern "C" void kernel_launch(void* const* d_in, const int* in_sizes, int n_in,
                              void* d_out, int out_size, void* d_ws, size_t ws_size,
                              hipStream_t stream) {
    const float* x = (const float*)d_in[0];   // [F,B,D]
    const float* w = (const float*)d_in[1];   // [F,D,K]
    float* out = (float*)d_out;

    if (ws_size >= (size_t)WS_NEED) {
        ushort* xh   = (ushort*)((char*)d_ws + XH_OFF);
        ushort* xl   = (ushort*)((char*)d_ws + XL_OFF);
        ushort* whT  = (ushort*)((char*)d_ws + WHT_OFF);
        ushort* wlT  = (ushort*)((char*)d_ws + WLT_OFF);
        float*  wt   = (float*)((char*)d_ws + WT_OFF);
        float*  wsq  = (float*)((char*)d_ws + WSQ_OFF);
        int2*   top2 = (int2*)((char*)d_ws + TOP2_OFF);
        double* lossAcc = (double*)((char*)d_ws + LOSS_OFF);

        init_kernel<<<1, 64, 0, stream>>>(lossAcc);
        split_x<<<dim3(F * B * D / 1024), 256, 0, stream>>>(x, xh, xl);
        transpose_split_w<<<dim3(K / 32, D / 32, F), dim3(32, 8), 0, stream>>>(w, wt, whT, wlT);
        compute_wsq<<<dim3(F * K / 256), 256, 0, stream>>>(w, wsq);
        gemm_mfma_top2<<<dim3(B / 128, F), 256, 0, stream>>>(xh, xl, whT, wlT, wsq, top2);
        refine_gather<<<dim3(F * B / 4), 256, 0, stream>>>(x, wt, top2, out, lossAcc);
        finish_loss<<<1, 64, 0, stream>>>(lossAcc, out + (size_t)F * B * D);
    } else {
        float*  wt   = (float*)((char*)d_ws + WT2_OFF);
        float*  wsq  = (float*)((char*)d_ws + WSQ2_OFF);
        int2*   top2 = (int2*)((char*)d_ws + TOP22_OFF);
        double* lossAcc = (double*)((char*)d_ws + LOSS2_OFF);

        init_kernel<<<1, 64, 0, stream>>>(lossAcc);
        transpose_w<<<dim3(K / 32, D / 32, F), dim3(32, 8), 0, stream>>>(w, wt);
        compute_wsq<<<dim3(F * K / 256), 256, 0, stream>>>(w, wsq);
        gemm_top2<<<dim3(B / BM, F), 256, 0, stream>>>(x, w, wsq, top2);
        refine_gather<<<dim3(F * B / 4), 256, 0, stream>>>(x, wt, top2, out, lossAcc);
        finish_loss<<<1, 64, 0, stream>>>(lossAcc, out + (size_t)F * B * D);
    }
}

// Round 3
// 435.338 us; speedup vs baseline: 2.0429x; 1.3494x over previous
//
#include <hip/hip_runtime.h>
#include <hip/hip_bf16.h>
#include <cstdint>
#include <cfloat>

#define F 16
#define B 4096
#define D 256
#define K 1024

typedef __attribute__((ext_vector_type(8))) short bf16x8;
typedef __attribute__((ext_vector_type(4))) float f32x4;

// ---- workspace layout (bytes) ----
#define XH_OFF   0u            // F*B*D bf16 = 33554432
#define XL_OFF   33554432u
#define WHT_OFF  67108864u     // F*K*D bf16 (transposed [f][k][d]) = 8388608
#define WLT_OFF  75497472u
#define WT_OFF   83886080u     // F*K*D fp32 (transposed) = 16777216
#define WSQ_OFF  100663296u    // F*K fp32
#define TOP2_OFF 100728832u    // F*B int2
#define LOSS_OFF 101253120u

__device__ __forceinline__ void async_load16(const void* g, void* l) {
    __builtin_amdgcn_global_load_lds(
        (const __attribute__((address_space(1))) void*)g,
        (__attribute__((address_space(3))) void*)l, 16, 0, 0);
}

// ---------------- init ----------------
__global__ void init_kernel(double* lossAcc) {
    if (threadIdx.x == 0) *lossAcc = 0.0;
}

// ---------------- split x into bf16 hi/lo ----------------
__global__ void split_x(const float* __restrict__ x, ushort* __restrict__ xh,
                        ushort* __restrict__ xl) {
    int i = (blockIdx.x * 256 + threadIdx.x) * 4;
    float4 v = *(const float4*)(x + i);
    ushort4 h, l;
#pragma unroll
    for (int j = 0; j < 4; ++j) {
        float fv = ((const float*)&v)[j];
        __hip_bfloat16 hb = __float2bfloat16(fv);
        float hf = __bfloat162float(hb);
        __hip_bfloat16 lb = __float2bfloat16(fv - hf);
        ((ushort*)&h)[j] = *(ushort*)&hb;
        ((ushort*)&l)[j] = *(ushort*)&lb;
    }
    *(ushort4*)(xh + i) = h;
    *(ushort4*)(xl + i) = l;
}

// ---------------- transpose w -> wt fp32 [f][k][d], + bf16 hi/lo ----------------
__global__ void transpose_split_w(const float* __restrict__ w, float* __restrict__ wt,
                                  ushort* __restrict__ whT, ushort* __restrict__ wlT) {
    __shared__ float sd[32][33];
    int f  = blockIdx.z;
    int k0 = blockIdx.x * 32;
    int d0 = blockIdx.y * 32;
    const float* wf = w + (size_t)f * D * K;
    size_t obase = (size_t)f * K * D;
    int tx = threadIdx.x, ty = threadIdx.y;
#pragma unroll
    for (int i = 0; i < 4; ++i) {
        int d = ty + i * 8;
        sd[d][tx] = wf[(size_t)(d0 + d) * K + (k0 + tx)];
    }
    __syncthreads();
#pragma unroll
    for (int i = 0; i < 4; ++i) {
        int k = ty + i * 8;
        float v = sd[tx][k];
        size_t o = obase + (size_t)(k0 + k) * D + (d0 + tx);
        wt[o] = v;
        __hip_bfloat16 hb = __float2bfloat16(v);
        float hf = __bfloat162float(hb);
        __hip_bfloat16 lb = __float2bfloat16(v - hf);
        whT[o] = *(ushort*)&hb;
        wlT[o] = *(ushort*)&lb;
    }
}

// ---------------- ||w_k||^2 fp32 ----------------
__global__ void compute_wsq(const float* __restrict__ w, float* __restrict__ wsq) {
    int idx = blockIdx.x * blockDim.x + threadIdx.x;
    int f = idx >> 10;
    int k = idx & (K - 1);
    const float* wf = w + (size_t)f * D * K + k;
    float acc = 0.f;
#pragma unroll 8
    for (int d = 0; d < D; ++d) {
        float v = wf[(size_t)d * K];
        acc = fmaf(v, v, acc);
    }
    wsq[idx] = acc;
}

// ---------------- MFMA split-bf16 GEMM + top-2, A resident in LDS ----------------
// LDS (ushort units): Ah [0,16384)  Al [16384,32768)
//                     Wbuf p at 32768 + p*16384 : wh [0,8192) wl [8192,16384)
__global__ __launch_bounds__(512, 2) void gemm_mfma_top2(
        const ushort* __restrict__ xh, const ushort* __restrict__ xl,
        const ushort* __restrict__ whT, const ushort* __restrict__ wlT,
        const float* __restrict__ wsq, int2* __restrict__ top2)
{
    __shared__ ushort lds[65536];   // 128 KiB
    const int bid  = blockIdx.x;
    const int f    = bid >> 6;            // consecutive 64 blocks share f -> W stays L2-hot
    const int m0   = (bid & 63) * 64;
    const int tid  = threadIdx.x;
    const int wave = tid >> 6, lane = tid & 63;
    const int mw   = wave >> 2;           // 0..1 : 32-row half
    const int nw   = wave & 3;            // 0..3 : 32-col quarter of 128-chunk
    const int quad = lane >> 4, l15 = lane & 15;

    const ushort* xhb = xh  + ((size_t)f * B + m0) * D;
    const ushort* xlb = xl  + ((size_t)f * B + m0) * D;
    const ushort* whb = whT + (size_t)f * K * D;
    const ushort* wlb = wlT + (size_t)f * K * D;

    // ---- prologue: stage A once (64 rows x 256 d, h+l), low-3-seg XOR swizzle
#pragma unroll
    for (int r = 0; r < 4; ++r) {
        int linear = (r * 8 + wave) * 64 + lane;      // 0..2047
        int row = linear >> 5, phys = linear & 31;
        int slog = (phys & 24) | ((phys ^ row) & 7);
        async_load16(xhb + (size_t)row * D + slog * 8, lds + linear * 8);
        async_load16(xlb + (size_t)row * D + slog * 8, lds + 16384 + linear * 8);
    }
    // ---- stage W chunk (n0=0,d0=0) into buf0
    {
        ushort* wb = lds + 32768;
#pragma unroll
        for (int r2 = 0; r2 < 2; ++r2) {
            int linear = (r2 * 8 + wave) * 64 + lane;  // 0..1023
            int row = linear >> 3, phys = linear & 7;
            int slog = phys ^ (row & 7);
            async_load16(whb + (size_t)row * D + slog * 8, wb + linear * 8);
            async_load16(wlb + (size_t)row * D + slog * 8, wb + 8192 + linear * 8);
        }
    }

    float v1[8], v2[8];
    int   i1[8], i2[8];
#pragma unroll
    for (int s = 0; s < 8; ++s) {
        v1[s] = FLT_MAX; v2[s] = FLT_MAX; i1[s] = 0x7fffffff; i2[s] = 0x7fffffff;
    }

    int parity = 0;
    for (int n0 = 0; n0 < K; n0 += 128) {
        f32x4 acc[2][2];
#pragma unroll
        for (int mt = 0; mt < 2; ++mt)
#pragma unroll
            for (int nt = 0; nt < 2; ++nt)
                acc[mt][nt] = (f32x4){0.f, 0.f, 0.f, 0.f};

        for (int d0 = 0; d0 < D; d0 += 64) {
            // prefetch next W chunk into the other buffer
            int nn = (d0 == 192) ? n0 + 128 : n0;
            int nd = (d0 == 192) ? 0 : d0 + 64;
            if (nn < K) {
                ushort* wb = lds + 32768 + (1 - parity) * 16384;
#pragma unroll
                for (int r2 = 0; r2 < 2; ++r2) {
                    int linear = (r2 * 8 + wave) * 64 + lane;
                    int row = linear >> 3, phys = linear & 7;
                    int slog = phys ^ (row & 7);
                    async_load16(whb + (size_t)(nn + row) * D + nd + slog * 8, wb + linear * 8);
                    async_load16(wlb + (size_t)(nn + row) * D + nd + slog * 8, wb + 8192 + linear * 8);
                }
            }
            __syncthreads();   // drains A (first iter) + current W chunk (+ prefetch)

            const ushort* wbase = lds + 32768 + parity * 16384;
#pragma unroll
            for (int ks = 0; ks < 2; ++ks) {
                bf16x8 ah[2], al[2];
#pragma unroll
                for (int mt = 0; mt < 2; ++mt) {
                    int row_a = mw * 32 + mt * 16 + l15;
                    int sA = (d0 >> 3) + ks * 4 + quad;
                    int phys = (sA & 24) | ((sA ^ row_a) & 7);
                    int off = row_a * 256 + phys * 8;
                    ah[mt] = *(const bf16x8*)(lds + off);
                    al[mt] = *(const bf16x8*)(lds + 16384 + off);
                }
#pragma unroll
                for (int nt = 0; nt < 2; ++nt) {
                    int row_b = nw * 32 + nt * 16 + l15;
                    int phys = ((ks * 4 + quad) ^ (row_b & 7));
                    int off = row_b * 64 + phys * 8;
                    bf16x8 bh = *(const bf16x8*)(wbase + off);
                    bf16x8 bl = *(const bf16x8*)(wbase + 8192 + off);
#pragma unroll
                    for (int mt = 0; mt < 2; ++mt) {
                        acc[mt][nt] = __builtin_amdgcn_mfma_f32_16x16x32_bf16(ah[mt], bh, acc[mt][nt], 0, 0, 0);
                        acc[mt][nt] = __builtin_amdgcn_mfma_f32_16x16x32_bf16(ah[mt], bl, acc[mt][nt], 0, 0, 0);
                        acc[mt][nt] = __builtin_amdgcn_mfma_f32_16x16x32_bf16(al[mt], bh, acc[mt][nt], 0, 0, 0);
                    }
                }
            }
            __syncthreads();   // protect buffer we stage into next iteration
            parity ^= 1;
        }

        // epilogue: scores -> per-lane running top-2
#pragma unroll
        for (int nt = 0; nt < 2; ++nt) {
            float wq = wsq[f * K + n0 + nw * 32 + nt * 16 + l15];
            int idx = n0 + nw * 32 + nt * 16 + l15;
#pragma unroll
            for (int mt = 0; mt < 2; ++mt) {
#pragma unroll
                for (int r = 0; r < 4; ++r) {
                    int s = mt * 4 + r;
                    float sc = fmaf(-2.f, acc[mt][nt][r], wq);
                    if (sc < v1[s]) { v2[s] = v1[s]; i2[s] = i1[s]; v1[s] = sc; i1[s] = idx; }
                    else if (sc < v2[s]) { v2[s] = sc; i2[s] = idx; }
                }
            }
        }
    }

    // cross-lane merge among the 16 l15 lanes (same quad)
#pragma unroll
    for (int s = 0; s < 8; ++s) {
#pragma unroll
        for (int off = 1; off < 16; off <<= 1) {
            float ov1 = __shfl_xor(v1[s], off);
            int   oi1 = __shfl_xor(i1[s], off);
            float ov2 = __shfl_xor(v2[s], off);
            int   oi2 = __shfl_xor(i2[s], off);
            bool sw = (ov1 < v1[s]) || (ov1 == v1[s] && oi1 < i1[s]);
            float a1 = sw ? ov1 : v1[s]; int a1i = sw ? oi1 : i1[s];
            float b1 = sw ? v1[s] : ov1; int b1i = sw ? i1[s] : oi1;
            float a2 = sw ? ov2 : v2[s]; int a2i = sw ? oi2 : i2[s];
            bool rp = (b1 < a2) || (b1 == a2 && b1i < a2i);
            v1[s] = a1;            i1[s] = a1i;
            v2[s] = rp ? b1 : a2;  i2[s] = rp ? b1i : a2i;
        }
    }

    // cross-wave (nw) merge via LDS (A region, no longer needed)
    __syncthreads();
    float* mrg = (float*)lds;     // [2 mw][32 row][4 nw][4] floats
    if (l15 == 0) {
#pragma unroll
        for (int mt = 0; mt < 2; ++mt)
#pragma unroll
            for (int r = 0; r < 4; ++r) {
                int s = mt * 4 + r;
                int rl = mt * 16 + quad * 4 + r;
                int e = ((mw * 32 + rl) * 4 + nw) * 4;
                mrg[e + 0] = v1[s]; ((int*)mrg)[e + 1] = i1[s];
                mrg[e + 2] = v2[s]; ((int*)mrg)[e + 3] = i2[s];
            }
    }
    __syncthreads();
    if (nw == 0 && l15 == 0) {
#pragma unroll
        for (int mt = 0; mt < 2; ++mt)
#pragma unroll
            for (int r = 0; r < 4; ++r) {
                int s = mt * 4 + r;
                int rl = mt * 16 + quad * 4 + r;
                float bv1 = v1[s], bv2 = v2[s];
                int   bi1 = i1[s], bi2 = i2[s];
#pragma unroll
                for (int q = 1; q < 4; ++q) {
                    int e = ((mw * 32 + rl) * 4 + q) * 4;
                    float ov1 = mrg[e + 0], ov2 = mrg[e + 2];
                    int   oi1 = ((int*)mrg)[e + 1], oi2 = ((int*)mrg)[e + 3];
                    bool sw = (ov1 < bv1) || (ov1 == bv1 && oi1 < bi1);
                    float a1 = sw ? ov1 : bv1; int a1i = sw ? oi1 : bi1;
                    float b1 = sw ? bv1 : ov1; int b1i = sw ? bi1 : oi1;
                    float a2 = sw ? ov2 : bv2; int a2i = sw ? oi2 : bi2;
                    bool rp = (b1 < a2) || (b1 == a2 && b1i < a2i);
                    bv1 = a1; bi1 = a1i;
                    bv2 = rp ? b1 : a2; bi2 = rp ? b1i : a2i;
                }
                top2[(size_t)f * B + m0 + mw * 32 + rl] = make_int2(bi1, bi2);
            }
    }
}

// ---------------- fp64 refine + gather + loss (1 atomic per block) ----------------
__global__ __launch_bounds__(256) void refine_gather(
        const float* __restrict__ x, const float* __restrict__ wt,
        const int2* __restrict__ top2, float* __restrict__ out,
        double* __restrict__ lossAcc) {
    __shared__ double lpart[4];
    int tid  = threadIdx.x;
    int wv   = tid >> 6;
    int lane = tid & 63;
    double lsum = 0.0;
    for (int it = 0; it < 16; ++it) {
        size_t row = ((size_t)blockIdx.x * 16 + it) * 4 + wv;
        int f = (int)(row >> 12);
        int2 cand = top2[row];
        const float* xr = x  + row * D;
        const float* w1 = wt + ((size_t)f * K + cand.x) * D;
        const float* w2 = wt + ((size_t)f * K + cand.y) * D;
        float4 xv = ((const float4*)xr)[lane];
        float4 a  = ((const float4*)w1)[lane];
        float4 b  = ((const float4*)w2)[lane];
        double s1 = 0.0, s2 = 0.0;
#pragma unroll
        for (int j = 0; j < 4; ++j) {
            double d1 = (double)((const float*)&xv)[j] - (double)((const float*)&a)[j];
            double d2 = (double)((const float*)&xv)[j] - (double)((const float*)&b)[j];
            s1 = fma(d1, d1, s1);
            s2 = fma(d2, d2, s2);
        }
#pragma unroll
        for (int off = 1; off < 64; off <<= 1) {
            s1 += __shfl_xor(s1, off);
            s2 += __shfl_xor(s2, off);
        }
        bool pick2 = (s2 < s1) || (s2 == s1 && cand.y < cand.x);
        float4 q = pick2 ? b : a;
        ((float4*)(out + row * D))[lane] = q;
        if (lane == 0) lsum += pick2 ? s2 : s1;
    }
    if (lane == 0) lpart[wv] = lsum;
    __syncthreads();
    if (tid == 0) {
        double t = lpart[0] + lpart[1] + lpart[2] + lpart[3];
        atomicAdd(lossAcc, t);
    }
}

__global__ void finish_loss(const double* __restrict__ lossAcc,
                            float* __restrict__ out_loss) {
    if (threadIdx.x == 0)
        *out_loss = (float)(0.25 * (*lossAcc) / ((double)F * (double)B * (double)D));
}

extern "C" void kernel_launch(void* const* d_in, const int* in_sizes, int n_in,
                              void* d_out, int out_size, void* d_ws, size_t ws_size,
                              hipStream_t stream) {
    const float* x = (const float*)d_in[0];   // [F,B,D]
    const float* w = (const float*)d_in[1];   // [F,D,K]
    float* out = (float*)d_out;

    ushort* xh   = (ushort*)((char*)d_ws + XH_OFF);
    ushort* xl   = (ushort*)((char*)d_ws + XL_OFF);
    ushort* whT  = (ushort*)((char*)d_ws + WHT_OFF);
    ushort* wlT  = (ushort*)((char*)d_ws + WLT_OFF);
    float*  wt   = (float*)((char*)d_ws + WT_OFF);
    float*  wsq  = (float*)((char*)d_ws + WSQ_OFF);
    int2*   top2 = (int2*)((char*)d_ws + TOP2_OFF);
    double* lossAcc = (double*)((char*)d_ws + LOSS_OFF);

    init_kernel<<<1, 64, 0, stream>>>(lossAcc);
    split_x<<<dim3(F * B * D / 1024), 256, 0, stream>>>(x, xh, xl);
    transpose_split_w<<<dim3(K / 32, D / 32, F), dim3(32, 8), 0, stream>>>(w, wt, whT, wlT);
    compute_wsq<<<dim3(F * K / 256), 256, 0, stream>>>(w, wsq);
    gemm_mfma_top2<<<dim3((B / 64) * F), 512, 0, stream>>>(xh, xl, whT, wlT, wsq, top2);
    refine_gather<<<dim3(F * B / 64), 256, 0, stream>>>(x, wt, top2, out, lossAcc);
    finish_loss<<<1, 64, 0, stream>>>(lossAcc, out + (size_t)F * B * D);
}

// Round 4
// 385.253 us; speedup vs baseline: 2.3085x; 1.1300x over previous
//
#include <hip/hip_runtime.h>
#include <hip/hip_bf16.h>
#include <cstdint>
#include <cfloat>

#define F 16
#define B 4096
#define D 256
#define K 1024

typedef __attribute__((ext_vector_type(8))) short bf16x8;
typedef __attribute__((ext_vector_type(4))) float f32x4;

// ---- workspace layout (bytes) ----
#define XH_OFF   0u            // F*B*D bf16 = 33554432
#define XL_OFF   33554432u
#define WHT_OFF  67108864u     // F*K*D bf16 transposed [f][k][d]
#define WLT_OFF  75497472u
#define WT_OFF   83886080u     // F*K*D fp32 transposed
#define WSQ_OFF  100663296u    // F*K fp32
#define TOP2_OFF 100728832u    // F*B float4 {v1, i1, v2, i2} = 1 MB
#define LOSS_OFF 101777408u

__device__ __forceinline__ void async_load16(const void* g, void* l) {
    __builtin_amdgcn_global_load_lds(
        (const __attribute__((address_space(1))) void*)g,
        (__attribute__((address_space(3))) void*)l, 16, 0, 0);
}

// ---------------- init: zero wsq + loss ----------------
__global__ void init_kernel(float* __restrict__ wsq, double* __restrict__ lossAcc) {
    int i = blockIdx.x * 256 + threadIdx.x;
    if (i < F * K) wsq[i] = 0.f;
    if (i == 0) *lossAcc = 0.0;
}

// ---------------- split x into bf16 hi/lo ----------------
__global__ void split_x(const float* __restrict__ x, ushort* __restrict__ xh,
                        ushort* __restrict__ xl) {
    int i = (blockIdx.x * 256 + threadIdx.x) * 4;
    float4 v = *(const float4*)(x + i);
    ushort4 h, l;
#pragma unroll
    for (int j = 0; j < 4; ++j) {
        float fv = ((const float*)&v)[j];
        __hip_bfloat16 hb = __float2bfloat16(fv);
        float hf = __bfloat162float(hb);
        __hip_bfloat16 lb = __float2bfloat16(fv - hf);
        ((ushort*)&h)[j] = *(ushort*)&hb;
        ((ushort*)&l)[j] = *(ushort*)&lb;
    }
    *(ushort4*)(xh + i) = h;
    *(ushort4*)(xl + i) = l;
}

// ------- transpose w -> wt fp32 [f][k][d] + bf16 hi/lo + fused ||w_k||^2 -------
__global__ void transpose_split_w(const float* __restrict__ w, float* __restrict__ wt,
                                  ushort* __restrict__ whT, ushort* __restrict__ wlT,
                                  float* __restrict__ wsq) {
    __shared__ float sd[32][33];
    int f  = blockIdx.z;
    int k0 = blockIdx.x * 32;
    int d0 = blockIdx.y * 32;
    const float* wf = w + (size_t)f * D * K;
    size_t obase = (size_t)f * K * D;
    int tx = threadIdx.x, ty = threadIdx.y;
#pragma unroll
    for (int i = 0; i < 4; ++i) {
        int d = ty + i * 8;
        sd[d][tx] = wf[(size_t)(d0 + d) * K + (k0 + tx)];
    }
    __syncthreads();
#pragma unroll
    for (int i = 0; i < 4; ++i) {
        int k = ty + i * 8;
        float v = sd[tx][k];
        size_t o = obase + (size_t)(k0 + k) * D + (d0 + tx);
        wt[o] = v;
        __hip_bfloat16 hb = __float2bfloat16(v);
        float hf = __bfloat162float(hb);
        __hip_bfloat16 lb = __float2bfloat16(v - hf);
        whT[o] = *(ushort*)&hb;
        wlT[o] = *(ushort*)&lb;
        // fused wsq: reduce v^2 over the 32 tx lanes (d within tile)
        float p = v * v;
#pragma unroll
        for (int off = 1; off < 32; off <<= 1) p += __shfl_xor(p, off);
        if (tx == 0) atomicAdd(&wsq[f * K + k0 + k], p);
    }
}

// ---------------- MFMA split-bf16 GEMM + top-2 ----------------
// A (64 rows, full D, h+l) resident in LDS seg-major; W streamed 16 KB/stage.
// LDS ushort units: Ah [0,16384)  Al [16384,32768)  Wh [32768,36864)  Wl [36864,40960)
__global__ __launch_bounds__(512, 4) void gemm_mfma_top2(
        const ushort* __restrict__ xh, const ushort* __restrict__ xl,
        const ushort* __restrict__ whT, const ushort* __restrict__ wlT,
        const float* __restrict__ wsq, float4* __restrict__ top2v)
{
    __shared__ ushort lds[40960];   // 80 KiB -> 2 blocks/CU
    const int bid  = blockIdx.x;
    const int f    = bid >> 6;             // 64 consecutive blocks share f (W L2-hot)
    const int m0   = (bid & 63) * 64;
    const int tid  = threadIdx.x;
    const int lane = tid & 63;
    const int wave = tid >> 6;             // 0..7
    const int mw   = wave >> 2;            // 0..1 : 32-row half
    const int nw   = wave & 3;             // 0..3 : 32-col quarter of the 128-chunk
    const int quad = lane >> 4, l15 = lane & 15;

    const ushort* xhb = xh  + ((size_t)f * B + m0) * D;
    const ushort* xlb = xl  + ((size_t)f * B + m0) * D;
    const ushort* whb = whT + (size_t)f * K * D;
    const ushort* wlb = wlT + (size_t)f * K * D;

    // ---- prologue: stage A seg-major [seg 0..31][row 0..63][8]
#pragma unroll
    for (int i = 0; i < 4; ++i) {
        int linear = i * 512 + tid;        // 0..2047 float4-slots
        int s = linear >> 6, row = linear & 63;
        async_load16(xhb + (size_t)row * D + s * 8, lds + linear * 8);
        async_load16(xlb + (size_t)row * D + s * 8, lds + 16384 + linear * 8);
    }

    float v1[8], v2[8];
    int   i1[8], i2[8];
#pragma unroll
    for (int s = 0; s < 8; ++s) {
        v1[s] = FLT_MAX; v2[s] = FLT_MAX; i1[s] = 0x7fffffff; i2[s] = 0x7fffffff;
    }

    // W staging indices (constant per thread)
    const int wq_ = tid >> 7;              // seg 0..3
    const int wn_ = tid & 127;             // n 0..127

    for (int n0 = 0; n0 < K; n0 += 128) {
        f32x4 acc[2][2];
#pragma unroll
        for (int mt = 0; mt < 2; ++mt)
#pragma unroll
            for (int nt = 0; nt < 2; ++nt)
                acc[mt][nt] = (f32x4){0.f, 0.f, 0.f, 0.f};

        const ushort* wh_n = whb + (size_t)(n0 + wn_) * D + wq_ * 8;
        const ushort* wl_n = wlb + (size_t)(n0 + wn_) * D + wq_ * 8;

        for (int d0 = 0; d0 < D; d0 += 32) {
            __syncthreads();   // previous stage's reads done; buffer reusable
            async_load16(wh_n + d0, lds + 32768 + tid * 8);
            async_load16(wl_n + d0, lds + 36864 + tid * 8);
            __syncthreads();   // loads visible (barrier drains vmcnt)

            const int sA = (d0 >> 3) + quad;
            bf16x8 ah[2], al[2];
#pragma unroll
            for (int mt = 0; mt < 2; ++mt) {
                int off = sA * 512 + (mw * 32 + mt * 16 + l15) * 8;
                ah[mt] = *(const bf16x8*)(lds + off);
                al[mt] = *(const bf16x8*)(lds + 16384 + off);
            }
#pragma unroll
            for (int nt = 0; nt < 2; ++nt) {
                int offw = quad * 1024 + (nw * 32 + nt * 16 + l15) * 8;
                bf16x8 bh = *(const bf16x8*)(lds + 32768 + offw);
                bf16x8 bl = *(const bf16x8*)(lds + 36864 + offw);
#pragma unroll
                for (int mt = 0; mt < 2; ++mt) {
                    acc[mt][nt] = __builtin_amdgcn_mfma_f32_16x16x32_bf16(ah[mt], bh, acc[mt][nt], 0, 0, 0);
                    acc[mt][nt] = __builtin_amdgcn_mfma_f32_16x16x32_bf16(ah[mt], bl, acc[mt][nt], 0, 0, 0);
                    acc[mt][nt] = __builtin_amdgcn_mfma_f32_16x16x32_bf16(al[mt], bh, acc[mt][nt], 0, 0, 0);
                }
            }
        }

        // epilogue: fold 128-column chunk into per-lane top-2
#pragma unroll
        for (int nt = 0; nt < 2; ++nt) {
            int ng = n0 + nw * 32 + nt * 16 + l15;
            float wq = wsq[f * K + ng];
#pragma unroll
            for (int mt = 0; mt < 2; ++mt) {
#pragma unroll
                for (int r = 0; r < 4; ++r) {
                    int s = mt * 4 + r;
                    float sc = fmaf(-2.f, acc[mt][nt][r], wq);
                    if (sc < v1[s]) { v2[s] = v1[s]; i2[s] = i1[s]; v1[s] = sc; i1[s] = ng; }
                    else if (sc < v2[s]) { v2[s] = sc; i2[s] = ng; }
                }
            }
        }
    }

    // cross-lane merge among the 16 l15 lanes (fixed quad)
#pragma unroll
    for (int s = 0; s < 8; ++s) {
#pragma unroll
        for (int off = 1; off < 16; off <<= 1) {
            float ov1 = __shfl_xor(v1[s], off);
            int   oi1 = __shfl_xor(i1[s], off);
            float ov2 = __shfl_xor(v2[s], off);
            int   oi2 = __shfl_xor(i2[s], off);
            bool sw = (ov1 < v1[s]) || (ov1 == v1[s] && oi1 < i1[s]);
            float a1 = sw ? ov1 : v1[s]; int a1i = sw ? oi1 : i1[s];
            float b1 = sw ? v1[s] : ov1; int b1i = sw ? i1[s] : oi1;
            float a2 = sw ? ov2 : v2[s]; int a2i = sw ? oi2 : i2[s];
            bool rp = (b1 < a2) || (b1 == a2 && b1i < a2i);
            v1[s] = a1;            i1[s] = a1i;
            v2[s] = rp ? b1 : a2;  i2[s] = rp ? b1i : a2i;
        }
    }

    // cross-wave (nw 0..3) merge via LDS
    __syncthreads();                       // all compute/LDS reads done
    float4* mrg = (float4*)lds;            // [64 rows][4 nw] float4
    if (l15 == 0) {
#pragma unroll
        for (int mt = 0; mt < 2; ++mt)
#pragma unroll
            for (int r = 0; r < 4; ++r) {
                int s = mt * 4 + r;
                int rl = mw * 32 + mt * 16 + quad * 4 + r;
                mrg[rl * 4 + nw] = make_float4(v1[s], __int_as_float(i1[s]),
                                               v2[s], __int_as_float(i2[s]));
            }
    }
    __syncthreads();
    if (nw == 0 && l15 == 0) {
#pragma unroll
        for (int mt = 0; mt < 2; ++mt)
#pragma unroll
            for (int r = 0; r < 4; ++r) {
                int rl = mw * 32 + mt * 16 + quad * 4 + r;
                float4 t0 = mrg[rl * 4 + 0];
                float bv1 = t0.x, bv2 = t0.z;
                int   bi1 = __float_as_int(t0.y), bi2 = __float_as_int(t0.w);
#pragma unroll
                for (int q = 1; q < 4; ++q) {
                    float4 tq = mrg[rl * 4 + q];
                    float ov1 = tq.x, ov2 = tq.z;
                    int   oi1 = __float_as_int(tq.y), oi2 = __float_as_int(tq.w);
                    bool sw = (ov1 < bv1) || (ov1 == bv1 && oi1 < bi1);
                    float a1 = sw ? ov1 : bv1; int a1i = sw ? oi1 : bi1;
                    float b1 = sw ? bv1 : ov1; int b1i = sw ? bi1 : oi1;
                    float a2 = sw ? ov2 : bv2; int a2i = sw ? oi2 : bi2;
                    bool rp = (b1 < a2) || (b1 == a2 && b1i < a2i);
                    bv1 = a1; bi1 = a1i;
                    bv2 = rp ? b1 : a2; bi2 = rp ? b1i : a2i;
                }
                top2v[(size_t)f * B + m0 + rl] =
                    make_float4(bv1, __int_as_float(bi1), bv2, __int_as_float(bi2));
            }
    }
}

// -------- fp64 refine + gather + loss; skip 2nd gather when gap is safe --------
__global__ __launch_bounds__(256) void refine_gather(
        const float* __restrict__ x, const float* __restrict__ wt,
        const float4* __restrict__ top2v, float* __restrict__ out,
        double* __restrict__ lossAcc) {
    __shared__ double lpart[4];
    int tid  = threadIdx.x;
    int wv   = tid >> 6;
    int lane = tid & 63;
    double lsum = 0.0;
    for (int it = 0; it < 16; ++it) {
        size_t row = ((size_t)blockIdx.x * 16 + it) * 4 + wv;
        int f = (int)(row >> 12);
        float4 t = top2v[row];
        int c1 = __float_as_int(t.y), c2 = __float_as_int(t.w);
        const float* xr = x  + row * D;
        const float* w1 = wt + ((size_t)f * K + c1) * D;
        float4 xv = ((const float4*)xr)[lane];
        float4 a  = ((const float4*)w1)[lane];
        double s1 = 0.0;
#pragma unroll
        for (int j = 0; j < 4; ++j) {
            double d1 = (double)((const float*)&xv)[j] - (double)((const float*)&a)[j];
            s1 = fma(d1, d1, s1);
        }
#pragma unroll
        for (int off = 1; off < 64; off <<= 1) s1 += __shfl_xor(s1, off);

        float4 q = a;
        double sel = s1;
        if (t.z - t.x < 2e-3f) {   // ambiguous: exact-check candidate 2 (wave-uniform)
            const float* w2 = wt + ((size_t)f * K + c2) * D;
            float4 b = ((const float4*)w2)[lane];
            double s2 = 0.0;
#pragma unroll
            for (int j = 0; j < 4; ++j) {
                double d2 = (double)((const float*)&xv)[j] - (double)((const float*)&b)[j];
                s2 = fma(d2, d2, s2);
            }
#pragma unroll
            for (int off = 1; off < 64; off <<= 1) s2 += __shfl_xor(s2, off);
            bool pick2 = (s2 < s1) || (s2 == s1 && c2 < c1);
            if (pick2) { q = b; sel = s2; }
        }
        ((float4*)(out + row * D))[lane] = q;
        if (lane == 0) lsum += sel;
    }
    if (lane == 0) lpart[wv] = lsum;
    __syncthreads();
    if (tid == 0) {
        double tsum = lpart[0] + lpart[1] + lpart[2] + lpart[3];
        atomicAdd(lossAcc, tsum);
    }
}

__global__ void finish_loss(const double* __restrict__ lossAcc,
                            float* __restrict__ out_loss) {
    if (threadIdx.x == 0)
        *out_loss = (float)(0.25 * (*lossAcc) / ((double)F * (double)B * (double)D));
}

extern "C" void kernel_launch(void* const* d_in, const int* in_sizes, int n_in,
                              void* d_out, int out_size, void* d_ws, size_t ws_size,
                              hipStream_t stream) {
    const float* x = (const float*)d_in[0];   // [F,B,D]
    const float* w = (const float*)d_in[1];   // [F,D,K]
    float* out = (float*)d_out;

    ushort* xh    = (ushort*)((char*)d_ws + XH_OFF);
    ushort* xl    = (ushort*)((char*)d_ws + XL_OFF);
    ushort* whT   = (ushort*)((char*)d_ws + WHT_OFF);
    ushort* wlT   = (ushort*)((char*)d_ws + WLT_OFF);
    float*  wt    = (float*)((char*)d_ws + WT_OFF);
    float*  wsq   = (float*)((char*)d_ws + WSQ_OFF);
    float4* top2v = (float4*)((char*)d_ws + TOP2_OFF);
    double* lossAcc = (double*)((char*)d_ws + LOSS_OFF);

    init_kernel<<<dim3(64), 256, 0, stream>>>(wsq, lossAcc);
    split_x<<<dim3(F * B * D / 1024), 256, 0, stream>>>(x, xh, xl);
    transpose_split_w<<<dim3(K / 32, D / 32, F), dim3(32, 8), 0, stream>>>(w, wt, whT, wlT, wsq);
    gemm_mfma_top2<<<dim3((B / 64) * F), 512, 0, stream>>>(xh, xl, whT, wlT, wsq, top2v);
    refine_gather<<<dim3(F * B / 64), 256, 0, stream>>>(x, wt, top2v, out, lossAcc);
    finish_loss<<<1, 64, 0, stream>>>(lossAcc, out + (size_t)F * B * D);
}